// Round 8
// baseline (133.763 us; speedup 1.0000x reference)
//
#include <hip/hip_runtime.h>
#include <math.h>

#define NB 2
#define NO 512
#define NQ 512
#define OUT_DIM 128
#define LPAD 516   // logits row pitch (floats): 16B-mult, bank-staggered

typedef __attribute__((ext_vector_type(8))) _Float16 half8;  // 4 VGPR
typedef __attribute__((ext_vector_type(4))) _Float16 half4;  // 2 VGPR
typedef __attribute__((ext_vector_type(4))) float f32x4;     // MFMA acc

__device__ __forceinline__ float softplus_f(float x) {
  return x > 0.0f ? x + log1pf(expf(-x)) : log1pf(expf(x));
}
__device__ __forceinline__ half8 splat8(_Float16 v) {
  return (half8){v, v, v, v, v, v, v, v};
}
__device__ __forceinline__ half8 fma8(half8 a, half8 b, half8 c) {
  return __builtin_elementwise_fma(a, b, c);
}
__device__ __forceinline__ half8 max8(half8 a, half8 b) {
  return __builtin_elementwise_max(a, b);
}
// async global->LDS, 16B per lane; dest = lds_base + lane*16 (wave-uniform base)
__device__ __forceinline__ void gll16(const void* g, void* l) {
  __builtin_amdgcn_global_load_lds(
      (const __attribute__((address_space(1))) unsigned int*)g,
      (__attribute__((address_space(3))) unsigned int*)l, 16, 0, 0);
}
// generic LDS pointer -> 32-bit LDS byte offset (for asm ds_* address operands)
__device__ __forceinline__ unsigned as3(const void* p) {
  return (unsigned)(unsigned long long)(const __attribute__((address_space(3))) char*)p;
}

// ---------------------------------------------------------------------------
// Prep: fused 2-layer MLP -> VT (f16, head-transposed [b][h][d][o]).
__global__ __launch_bounds__(1024) void prep_kernel(
    const float* __restrict__ h_obs, const float* __restrict__ fw1,
    const float* __restrict__ fb1, const float* __restrict__ fw2,
    const float* __restrict__ fb2, _Float16* __restrict__ VT)
{
  __shared__ float s_red[4][4][256];
  __shared__ float s_hid[4][256];
  const int n  = threadIdx.x & 255;
  const int ks = threadIdx.x >> 8;
  const int r0 = blockIdx.x * 4;
  const int k0 = ks * 64;
  float a0 = 0.f, a1 = 0.f, a2 = 0.f, a3 = 0.f;
  #pragma unroll 8
  for (int kk = 0; kk < 64; ++kk) {
    int k = k0 + kk;
    float w = fw1[k * 256 + n];
    a0 = fmaf(h_obs[(r0 + 0) * 256 + k], w, a0);
    a1 = fmaf(h_obs[(r0 + 1) * 256 + k], w, a1);
    a2 = fmaf(h_obs[(r0 + 2) * 256 + k], w, a2);
    a3 = fmaf(h_obs[(r0 + 3) * 256 + k], w, a3);
  }
  s_red[ks][0][n] = a0; s_red[ks][1][n] = a1;
  s_red[ks][2][n] = a2; s_red[ks][3][n] = a3;
  __syncthreads();
  if (ks == 0) {
    float bb = fb1[n];
    #pragma unroll
    for (int r = 0; r < 4; ++r) {
      float v = s_red[0][r][n] + s_red[1][r][n] + s_red[2][r][n] + s_red[3][r][n] + bb;
      s_hid[r][n] = fmaxf(v, 0.f);
    }
  }
  __syncthreads();
  float c0 = 0.f, c1 = 0.f, c2 = 0.f, c3 = 0.f;
  #pragma unroll 8
  for (int kk = 0; kk < 64; ++kk) {
    int k = k0 + kk;
    float w = fw2[k * 256 + n];
    c0 = fmaf(s_hid[0][k], w, c0);
    c1 = fmaf(s_hid[1][k], w, c1);
    c2 = fmaf(s_hid[2][k], w, c2);
    c3 = fmaf(s_hid[3][k], w, c3);
  }
  __syncthreads();
  s_red[ks][0][n] = c0; s_red[ks][1][n] = c1;
  s_red[ks][2][n] = c2; s_red[ks][3][n] = c3;
  __syncthreads();
  if (ks == 0) {
    float bb = fb2[n];
    float vr[4];
    #pragma unroll
    for (int r = 0; r < 4; ++r)
      vr[r] = s_red[0][r][n] + s_red[1][r][n] + s_red[2][r][n] + s_red[3][r][n] + bb;
    // transpose store: thread n owns column (h,d); 4 consecutive o
    const int h  = n >> 5, d = n & 31;
    const int bb_ = r0 >> 9, o0 = r0 & 511;
    half4 pv;
    #pragma unroll
    for (int r = 0; r < 4; ++r) pv[r] = (_Float16)vr[r];
    *(half4*)(VT + ((size_t)((bb_ * 8 + h) * 32 + d)) * 512 + o0) = pv;
  }
}

// ---------------------------------------------------------------------------
// Fused attention + out_proj. QT=2 per block, 512 threads (8 waves).
// Phase 1: f16 MFMA delta; ao built in-register (rank-3 pos projection).
// Phase 2+3: per-wave (=head), barrier-free. ALL LDS accesses from softmax
//   through PV are inline asm (ds_read/ds_write + manual counted waitcnts):
//   the HIP compiler must otherwise order every visible LDS access against
//   outstanding global_load_lds (may-alias) with vmcnt(0) drains, which
//   serializes the staged pipeline at full memory latency per K-step.
//   6-buffer (3-pair) rotation, steady-state vmcnt(4), 6 loads in flight.
//   (P-store uses ds_write2_b32 with SCALAR u32 inputs: clang rejects
//   128-bit vector asm INPUTS, vector outputs are fine.)
__global__ __launch_bounds__(512, 4) void attn_fused(
    const _Float16* __restrict__ VT,     // [b][h][d][o] f16
    const float* __restrict__ kw1,       // (9, 256)
    const float* __restrict__ kb1,       // (256)
    const float* __restrict__ kw2,       // (256, 8)
    const float* __restrict__ kb2,       // (8)
    const float* __restrict__ log_sigma, // (8)
    const float* __restrict__ pos_obs,   // (B*NO, 3)
    const float* __restrict__ pos_query, // (B*NQ, 3)
    const float* __restrict__ ow, const float* __restrict__ obias,
    const float* __restrict__ vw, const float* __restrict__ vbias,
    float* __restrict__ out)
{
  __shared__ __align__(16) float s_logits[2][8 * LPAD];   // 33024 B; ph3: stage pairs 1,2
  __shared__ __align__(16) _Float16 s_P16[2][8][520];     // 16640 B (P, f16)
  __shared__ half8 s_Bh[512];                             // 8192 B (kw2 frags; ph3: buf0)
  __shared__ __align__(16) float s_pool[2048];            // 8192 B (hv | pred; ph3: buf1 w0-3)
  __shared__ __align__(16) float s_po[3][516];            // 6192 B (pos SoA; ph3: buf1 w4-7)
  __shared__ __align__(16) _Float16 s_co[3][264];         // 1584 B (ao coeff table)

  _Float16* s_aq2 = (_Float16*)s_pool;   // [2][256] f16 (phase 1 only)
  float*    s_hv   = s_pool;             // [(q*2+kind)*256+hd] (phase 3/4)
  float*    s_pred = s_pool + 1024;      // [ks][mode][q][128]  (phase 4)

  const int t   = threadIdx.x;
  const int bq0 = blockIdx.x * 2;
  const int b   = bq0 >> 9;

  // ---- prologue -----------------------------------------------------------
  float pqx[2], pqy[2], pqz[2];
  #pragma unroll
  for (int q = 0; q < 2; ++q) {
    pqx[q] = pos_query[(bq0 + q) * 3 + 0];
    pqy[q] = pos_query[(bq0 + q) * 3 + 1];
    pqz[q] = pos_query[(bq0 + q) * 3 + 2];
  }
  // aq[q][j] in f16
  {
    const int q = t >> 8, j = t & 255;
    float c0 = kw1[0 * 256 + j] + kw1[6 * 256 + j];
    float c1 = kw1[1 * 256 + j] + kw1[7 * 256 + j];
    float c2 = kw1[2 * 256 + j] + kw1[8 * 256 + j];
    s_aq2[q * 256 + j] = (_Float16)
        fmaf(pqx[q], c0, fmaf(pqy[q], c1, fmaf(pqz[q], c2, kb1[j])));
  }
  // ao coefficient table (rank-3): co[c][j], f16
  if (t < 256) {
    const int j = t;
    s_co[0][j] = (_Float16)(kw1[3 * 256 + j] - kw1[6 * 256 + j]);
    s_co[1][j] = (_Float16)(kw1[4 * 256 + j] - kw1[7 * 256 + j]);
    s_co[2][j] = (_Float16)(kw1[5 * 256 + j] - kw1[8 * 256 + j]);
  }
  // pos_obs SoA + logits prefill (rbf + kb2) for o = t, both q, all h.
  // log(exp(x)+1e-8) ~= max(x, log(1e-8)); clamp region weight < e^-15.
  {
    const int o = t;
    const float* p = pos_obs + (size_t)(b * NO + o) * 3;
    float px = p[0], py = p[1], pz = p[2];
    s_po[0][o] = px; s_po[1][o] = py; s_po[2][o] = pz;
    float d2q[2];
    #pragma unroll
    for (int q = 0; q < 2; ++q) {
      float r0 = pqx[q] - px, r1 = pqy[q] - py, r2 = pqz[q] - pz;
      d2q[q] = r0 * r0 + r1 * r1 + r2 * r2;
    }
    #pragma unroll
    for (int h = 0; h < 8; ++h) {
      float sg  = __expf(log_sigma[h]);
      float inv = 1.0f / (sg * sg + 1e-6f);
      float kbv = kb2[h];
      s_logits[0][h * LPAD + o] = fmaxf(-d2q[0] * inv, -18.420681f) + kbv;
      s_logits[1][h * LPAD + o] = fmaxf(-d2q[1] * inv, -18.420681f) + kbv;
    }
  }
  // B fragments: kw2 as f16
  {
    const int kstep = t >> 6, lane = t & 63;
    const int nh = lane & 15;
    const int kb_ = kstep * 32 + ((lane >> 4) & 3) * 8;
    half8 b8;
    #pragma unroll
    for (int i = 0; i < 8; ++i) {
      float v = (nh < 8) ? kw2[(kb_ + i) * 8 + nh] : 0.f;
      b8[i] = (_Float16)v;
    }
    s_Bh[kstep * 64 + lane] = b8;
  }
  __syncthreads();

  // ---- phase 1: f16 MFMA delta; A = relu(aq + pos.co) all in packed f16 ---
  {
    const int wave = t >> 6, lane = t & 63;
    const int quad = lane >> 4, mrow = lane & 15;
    const int tb   = wave * 4;
    _Float16 pxh[4], pyh[4], pzh[4];
    #pragma unroll
    for (int jt = 0; jt < 4; ++jt) {
      const int o = (tb + jt) * 16 + mrow;
      pxh[jt] = (_Float16)s_po[0][o];
      pyh[jt] = (_Float16)s_po[1][o];
      pzh[jt] = (_Float16)s_po[2][o];
    }
    f32x4 C[2][4];
    #pragma unroll
    for (int q = 0; q < 2; ++q)
      #pragma unroll
      for (int jt = 0; jt < 4; ++jt) C[q][jt] = (f32x4){0.f, 0.f, 0.f, 0.f};

    const half8 z8 = {0, 0, 0, 0, 0, 0, 0, 0};
    #pragma unroll
    for (int kstep = 0; kstep < 8; ++kstep) {
      const int koff = kstep * 32 + quad * 8;
      half8 c0 = *(const half8*)&s_co[0][koff];
      half8 c1 = *(const half8*)&s_co[1][koff];
      half8 c2 = *(const half8*)&s_co[2][koff];
      half8 aq0 = *(const half8*)(s_aq2 + koff);
      half8 aq1 = *(const half8*)(s_aq2 + 256 + koff);
      half8 bh  = s_Bh[kstep * 64 + lane];
      #pragma unroll
      for (int jt = 0; jt < 4; ++jt) {
        half8 ao = fma8(splat8(pxh[jt]), c0,
                   fma8(splat8(pyh[jt]), c1, splat8(pzh[jt]) * c2));
        half8 a0 = max8(aq0 + ao, z8);
        half8 a1 = max8(aq1 + ao, z8);
        C[0][jt] = __builtin_amdgcn_mfma_f32_16x16x32_f16(a0, bh, C[0][jt], 0, 0, 0);
        C[1][jt] = __builtin_amdgcn_mfma_f32_16x16x32_f16(a1, bh, C[1][jt], 0, 0, 0);
      }
    }
    // epilogue: D[n=h=lane&15][m=quad*4+r]; add delta into prefilled logits
    const int hh = lane & 15;
    if (hh < 8) {
      #pragma unroll
      for (int q = 0; q < 2; ++q)
        #pragma unroll
        for (int jt = 0; jt < 4; ++jt) {
          const int ob2 = (tb + jt) * 16 + quad * 4;
          #pragma unroll
          for (int r = 0; r < 4; ++r)
            s_logits[q][hh * LPAD + ob2 + r] += C[q][jt][r];
        }
    }
  }
  __syncthreads();   // logits complete; waves drift from here to phase 4

  // ---- phase 2+3: per-wave (=head), barrier-free, asm-only LDS window -----
  {
    const int h = t >> 6, lane = t & 63;
    const int kg = lane >> 4, dl = lane & 15;
    // 6 wave-private 1KB staging buffers (3 pairs), all dead for others:
    char* B0 = (char*)s_Bh + h * 1024;                       // own kw2 slot
    char* B1 = (h < 4) ? ((char*)s_pool + 4096 + h * 1024)   // s_pred region
                       : ((char*)s_po + (h - 4) * 1024);     // pos SoA region
    char* B2 = (char*)&s_logits[0][h * LPAD];                // own q0 row
    char* B3 = B2 + 1024;
    char* B4 = (char*)&s_logits[1][h * LPAD];                // own q1 row
    char* B5 = B4 + 1024;
    // pre-swizzled SOURCE lane (LDS dest stays linear per gll rules)
    const int lp = lane ^ ((lane >> 3) & 1);
    const _Float16* vsrc = VT + ((size_t)(b * 8 + h) << 14)
                         + (lp >> 1) * 512 + (lp & 1) * 8;
    gll16(vsrc + 0 * 16, B0);          // slices 0,1 issued before softmax
    gll16(vsrc + 1 * 16, B1);

    // softmax: logits read via asm (no compiler vmcnt(0) drain vs the glls)
    unsigned l0A = as3(&s_logits[0][h * LPAD]) + lane * 32;
    unsigned l1A = as3(&s_logits[1][h * LPAD]) + lane * 32;
    int4 La, Lb, Lc, Ld;
    asm volatile("ds_read_b128 %0, %4\n\t"
                 "ds_read_b128 %1, %4 offset:16\n\t"
                 "ds_read_b128 %2, %5\n\t"
                 "ds_read_b128 %3, %5 offset:16\n\t"
                 "s_waitcnt lgkmcnt(0)"
                 : "=&v"(La), "=&v"(Lb), "=&v"(Lc), "=&v"(Ld)
                 : "v"(l0A), "v"(l1A) : "memory");
    f32x4 f0 = __builtin_bit_cast(f32x4, La);
    f32x4 f1 = __builtin_bit_cast(f32x4, Lb);
    f32x4 g0 = __builtin_bit_cast(f32x4, Lc);
    f32x4 g1 = __builtin_bit_cast(f32x4, Ld);
    // no-max softmax: p = exp(l - ln16); scale cancels in normalization
    float s0 = 0.f, s1 = 0.f;
    half8 P0, P1;
    #pragma unroll
    for (int k = 0; k < 4; ++k) {
      float p0 = __expf(f0[k] - 2.7725887f);
      float p1 = __expf(f1[k] - 2.7725887f);
      float p2 = __expf(g0[k] - 2.7725887f);
      float p3 = __expf(g1[k] - 2.7725887f);
      s0 += p0 + p1; s1 += p2 + p3;
      P0[k] = (_Float16)p0; P0[k + 4] = (_Float16)p1;
      P1[k] = (_Float16)p2; P1[k + 4] = (_Float16)p3;
    }
    {
      int4 P0v = __builtin_bit_cast(int4, P0);
      int4 P1v = __builtin_bit_cast(int4, P1);
      unsigned p0A = as3(&s_P16[0][h][0]) + lane * 16;
      unsigned p1A = as3(&s_P16[1][h][0]) + lane * 16;
      // scalar u32 inputs only (vector asm inputs unsupported by clang)
      asm volatile("ds_write2_b32 %0, %1, %2 offset0:0 offset1:1\n\t"
                   "ds_write2_b32 %0, %3, %4 offset0:2 offset1:3\n\t"
                   "ds_write2_b32 %5, %6, %7 offset0:0 offset1:1\n\t"
                   "ds_write2_b32 %5, %8, %9 offset0:2 offset1:3"
                   :: "v"(p0A), "v"(P0v.x), "v"(P0v.y), "v"(P0v.z), "v"(P0v.w),
                      "v"(p1A), "v"(P1v.x), "v"(P1v.y), "v"(P1v.z), "v"(P1v.w)
                   : "memory");
    }
    // own logits rows fully read -> staging; fill remaining 4 buffers
    gll16(vsrc + 2 * 16, B2);
    gll16(vsrc + 3 * 16, B3);
    gll16(vsrc + 4 * 16, B4);
    gll16(vsrc + 5 * 16, B5);

    // PV addresses (swizzled read slot; see r6 derivation)
    const int slot = ((kg & 1) ^ ((dl >> 2) & 1)) << 4;
    const unsigned amP0 = as3((kg < 2) ? B0 : B1) + dl * 32 + slot;
    const unsigned amP1 = as3((kg < 2) ? B2 : B3) + dl * 32 + slot;
    const unsigned amP2 = as3((kg < 2) ? B4 : B5) + dl * 32 + slot;
    const unsigned pbA  = as3(&s_P16[lane & 1][h][0]) + kg * 16;

    f32x4 Cm0 = {0.f, 0.f, 0.f, 0.f}, Cm1 = Cm0, Cv0 = Cm0, Cv1 = Cm0;
#define PVSTEP(s, AM, WN, REFILL)                                          \
    { asm volatile("s_waitcnt vmcnt(" WN ")" ::: "memory");                \
      int4 A0v, A1v, PBv;                                                  \
      asm volatile("ds_read_b128 %0, %3\n\t"                               \
                   "ds_read_b128 %1, %3 offset:512\n\t"                    \
                   "ds_read_b128 %2, %4\n\t"                               \
                   "s_waitcnt lgkmcnt(0)"                                  \
                   : "=&v"(A0v), "=&v"(A1v), "=&v"(PBv)                    \
                   : "v"(AM), "v"(pbA + (s) * 64)                          \
                   : "memory");                                            \
      half8 am0 = __builtin_bit_cast(half8, A0v);                          \
      half8 am1 = __builtin_bit_cast(half8, A1v);                          \
      half8 pb  = __builtin_bit_cast(half8, PBv);                          \
      half8 av0 = am0 * am0, av1 = am1 * am1;                              \
      __builtin_amdgcn_s_setprio(1);                                       \
      Cm0 = __builtin_amdgcn_mfma_f32_16x16x32_f16(am0, pb, Cm0, 0, 0, 0); \
      Cm1 = __builtin_amdgcn_mfma_f32_16x16x32_f16(am1, pb, Cm1, 0, 0, 0); \
      Cv0 = __builtin_amdgcn_mfma_f32_16x16x32_f16(av0, pb, Cv0, 0, 0, 0); \
      Cv1 = __builtin_amdgcn_mfma_f32_16x16x32_f16(av1, pb, Cv1, 0, 0, 0); \
      __builtin_amdgcn_s_setprio(0);                                       \
      REFILL }

    PVSTEP( 0, amP0, "4", gll16(vsrc +  6 * 16, B0); gll16(vsrc +  7 * 16, B1);)
    PVSTEP( 1, amP1, "4", gll16(vsrc +  8 * 16, B2); gll16(vsrc +  9 * 16, B3);)
    PVSTEP( 2, amP2, "4", gll16(vsrc + 10 * 16, B4); gll16(vsrc + 11 * 16, B5);)
    PVSTEP( 3, amP0, "4", gll16(vsrc + 12 * 16, B0); gll16(vsrc + 13 * 16, B1);)
    PVSTEP( 4, amP1, "4", gll16(vsrc + 14 * 16, B2); gll16(vsrc + 15 * 16, B3);)
    PVSTEP( 5, amP2, "4", gll16(vsrc + 16 * 16, B4); gll16(vsrc + 17 * 16, B5);)
    PVSTEP( 6, amP0, "4", gll16(vsrc + 18 * 16, B0); gll16(vsrc + 19 * 16, B1);)
    PVSTEP( 7, amP1, "4", gll16(vsrc + 20 * 16, B2); gll16(vsrc + 21 * 16, B3);)
    PVSTEP( 8, amP2, "4", gll16(vsrc + 22 * 16, B4); gll16(vsrc + 23 * 16, B5);)
    PVSTEP( 9, amP0, "4", gll16(vsrc + 24 * 16, B0); gll16(vsrc + 25 * 16, B1);)
    PVSTEP(10, amP1, "4", gll16(vsrc + 26 * 16, B2); gll16(vsrc + 27 * 16, B3);)
    PVSTEP(11, amP2, "4", gll16(vsrc + 28 * 16, B4); gll16(vsrc + 29 * 16, B5);)
    PVSTEP(12, amP0, "4", gll16(vsrc + 30 * 16, B0); gll16(vsrc + 31 * 16, B1);)
    PVSTEP(13, amP1, "4", )
    PVSTEP(14, amP2, "2", )
    PVSTEP(15, amP0, "0", )
#undef PVSTEP

    // deferred sum reduction (off the PV critical path)
    #pragma unroll
    for (int off = 32; off >= 1; off >>= 1) {
      s0 += __shfl_xor(s0, off, 64);
      s1 += __shfl_xor(s1, off, 64);
    }
    // epilogue: C row = kg*4+r (=d_local), col = nq (=q). Normalize + var.
    const int nq = lane & 15;
    if (nq < 2) {
      const float iv = 1.0f / (nq ? s1 : s0);
      const int dbase = h * 32 + kg * 4;
      f32x4 m0, v0, m1, v1;
      #pragma unroll
      for (int r = 0; r < 4; ++r) {
        float a = Cm0[r] * iv;
        m0[r] = a; v0[r] = fmaxf(Cv0[r] * iv - a * a, 0.f);
        float c = Cm1[r] * iv;
        m1[r] = c; v1[r] = fmaxf(Cv1[r] * iv - c * c, 0.f);
      }
      *(f32x4*)(s_hv + (nq * 2 + 0) * 256 + dbase)      = m0;
      *(f32x4*)(s_hv + (nq * 2 + 1) * 256 + dbase)      = v0;
      *(f32x4*)(s_hv + (nq * 2 + 0) * 256 + dbase + 16) = m1;
      *(f32x4*)(s_hv + (nq * 2 + 1) * 256 + dbase + 16) = v1;
    }
  }
  __syncthreads();

  // ---- phase 4: out_proj, k-split 2, W read once per (mode,ks) ------------
  {
    const int ks = t >> 8, mode = (t >> 7) & 1, n = t & 127;
    const float* W  = mode ? vw : ow;
    const float* X0 = s_hv + mode * 256;        // q0
    const float* X1 = s_hv + (2 + mode) * 256;  // q1
    float a0 = 0.f, a1 = 0.f;
    const int k0 = ks * 128;
    #pragma unroll 4
    for (int k = k0; k < k0 + 128; k += 4) {
      float4 x0 = *(const float4*)&X0[k];
      float4 x1 = *(const float4*)&X1[k];
      float w0 = W[(k + 0) * 128 + n];
      float w1 = W[(k + 1) * 128 + n];
      float w2 = W[(k + 2) * 128 + n];
      float w3 = W[(k + 3) * 128 + n];
      a0 = fmaf(x0.x, w0, a0); a1 = fmaf(x1.x, w0, a1);
      a0 = fmaf(x0.y, w1, a0); a1 = fmaf(x1.y, w1, a1);
      a0 = fmaf(x0.z, w2, a0); a1 = fmaf(x1.z, w2, a1);
      a0 = fmaf(x0.w, w3, a0); a1 = fmaf(x1.w, w3, a1);
    }
    s_pred[((ks * 2 + mode) * 2 + 0) * 128 + n] = a0;   // disjoint from s_hv
    s_pred[((ks * 2 + mode) * 2 + 1) * 128 + n] = a1;
  }
  __syncthreads();
  {
    const int q = t >> 8, mode = (t >> 7) & 1, n = t & 127;
    float v = s_pred[((0 * 2 + mode) * 2 + q) * 128 + n]
            + s_pred[((1 * 2 + mode) * 2 + q) * 128 + n]
            + (mode ? vbias[n] : obias[n]);
    if (mode) v = softplus_f(v);
    out[(size_t)mode * (NB * NQ * OUT_DIM) + (size_t)(bq0 + q) * OUT_DIM + n] = v;
  }
}

// ---------------------------------------------------------------------------
extern "C" void kernel_launch(void* const* d_in, const int* in_sizes, int n_in,
                              void* d_out, int out_size, void* d_ws, size_t ws_size,
                              hipStream_t stream)
{
  const float* h_obs     = (const float*)d_in[0];
  const float* pos_obs   = (const float*)d_in[1];
  const float* pos_query = (const float*)d_in[2];
  const float* fw1       = (const float*)d_in[3];
  const float* fb1       = (const float*)d_in[4];
  const float* fw2       = (const float*)d_in[5];
  const float* fb2       = (const float*)d_in[6];
  const float* log_sigma = (const float*)d_in[7];
  const float* kw1       = (const float*)d_in[8];
  const float* kb1       = (const float*)d_in[9];
  const float* kw2       = (const float*)d_in[10];
  const float* kb2       = (const float*)d_in[11];
  const float* ow        = (const float*)d_in[12];
  const float* ob        = (const float*)d_in[13];
  const float* vw        = (const float*)d_in[14];
  const float* vb        = (const float*)d_in[15];

  float* out = (float*)d_out;
  _Float16* VT = (_Float16*)d_ws;   // 262144 f16 = 512 KB

  prep_kernel<<<256, 1024, 0, stream>>>(h_obs, fw1, fb1, fw2, fb2, VT);
  attn_fused<<<NB * NQ / 2, 512, 0, stream>>>(VT, kw1, kb1, kw2, kb2,
                                              log_sigma, pos_obs, pos_query,
                                              ow, ob, vw, vb, out);
}